// Round 11
// baseline (625.831 us; speedup 1.0000x reference)
//
#include <hip/hip_runtime.h>
#include <hip/hip_bf16.h>

typedef _Float16 f16;
typedef _Float16 f16x8 __attribute__((ext_vector_type(8)));
typedef float f32x4 __attribute__((ext_vector_type(4)));

#define NBATCH 128
#define NTIME  128
#define NKIN   512
#define NUNITS 512
#define NGATE  2048

#define GROUPS 8    // batch groups: grp = bid & 7 (16 rows each)
#define SLOTS  32   // blocks per group: slot = bid >> 3 (16 unit-cols each)
#define GROWS  16   // batch rows per group
#define GUNITS 16   // unit-cols per block (x4 gates = 64 gate-cols)
#define HSZ    (NBATCH * NUNITS)   // one h slot (f16 elems)
#define POISON 0x7C00u             // f16 +inf: impossible as h = o*tanh(c)

static __device__ __forceinline__ float sigmoidf_(float x) {
    return 1.0f / (1.0f + __expf(-x));
}
static __device__ __forceinline__ float tanhf_(float x) {
    float t = __expf(-2.0f * fabsf(x));
    float r = (1.0f - t) / (1.0f + t);
    return copysignf(r, x);
}

static __device__ __forceinline__ f16x8 pack8(float4 a, float4 b) {
    f16x8 r;
    r[0] = (f16)a.x; r[1] = (f16)a.y; r[2] = (f16)a.z; r[3] = (f16)a.w;
    r[4] = (f16)b.x; r[5] = (f16)b.y; r[6] = (f16)b.z; r[7] = (f16)b.w;
    return r;
}

// ---- MALL-coherent (sc0 sc1) ops: bypass L1+L2; device-wide; proven r3/r4/r8 ----
static __device__ __forceinline__ void store_u16_sys(void* p, unsigned short v) {
    asm volatile("global_store_short %0, %1, off sc0 sc1" :: "v"(p), "v"(v) : "memory");
}
static __device__ __forceinline__ void store_16B_sys(void* p, f32x4 v) {
    asm volatile("global_store_dwordx4 %0, %1, off sc0 sc1" :: "v"(p), "v"(v) : "memory");
}
static __device__ __forceinline__ void load4x16_sys(const f16* p, f32x4* a, f32x4* b,
                                                    f32x4* c, f32x4* d) {
    asm volatile("global_load_dwordx4 %0, %4, off sc0 sc1\n\t"
                 "global_load_dwordx4 %1, %5, off sc0 sc1\n\t"
                 "global_load_dwordx4 %2, %6, off sc0 sc1\n\t"
                 "global_load_dwordx4 %3, %7, off sc0 sc1\n\t"
                 "s_waitcnt vmcnt(0)"
                 : "=&v"(*a), "=&v"(*b), "=&v"(*c), "=&v"(*d)
                 : "v"(p), "v"(p + 8), "v"(p + 16), "v"(p + 24) : "memory");
}

// true if no f16 half of the 16B chunk equals the poison pattern
static __device__ __forceinline__ int chunk_clean(f32x4 v) {
#pragma unroll
    for (int i = 0; i < 4; ++i) {
        unsigned u = __float_as_uint(v[i]);
        if ((u & 0xFFFFu) == POISON || (u >> 16) == POISON) return 0;
    }
    return 1;
}

// ---------------- poison init: fill 3 h slots with f16 +inf ----------------
__global__ __launch_bounds__(256)
void k_poison(f16* __restrict__ hsl) {
    f32x4 v;
    const float pf = __uint_as_float((POISON << 16) | POISON);
#pragma unroll
    for (int i = 0; i < 4; ++i) v[i] = pf;
    const size_t i = ((size_t)blockIdx.x * 256 + threadIdx.x) * 8;
    if (i < (size_t)3 * HSZ) *(f32x4*)(hsl + i) = v;
}

// ---------------- transpose: f32 in[512][2048] -> f16 out[2048][512] ----------------
__global__ __launch_bounds__(256)
void k_transpose(const float* __restrict__ in, f16* __restrict__ out) {
    __shared__ f16 tile[64][72];
    const int c0 = blockIdx.x * 64;
    const int r0 = blockIdx.y * 64;
    const int tid = threadIdx.x;
    {
        const int lr = tid >> 2;
        const int lc = (tid & 3) << 4;
        const float* src = in + (size_t)(r0 + lr) * NGATE + c0 + lc;
        float4 v0 = ((const float4*)src)[0];
        float4 v1 = ((const float4*)src)[1];
        float4 v2 = ((const float4*)src)[2];
        float4 v3 = ((const float4*)src)[3];
        *(f16x8*)&tile[lr][lc]     = pack8(v0, v1);
        *(f16x8*)&tile[lr][lc + 8] = pack8(v2, v3);
    }
    __syncthreads();
    {
        const int lc = tid >> 2;
        const int lr = (tid & 3) << 4;
        f16x8 a, b;
#pragma unroll
        for (int i = 0; i < 8; ++i) a[i] = tile[lr + i][lc];
#pragma unroll
        for (int i = 0; i < 8; ++i) b[i] = tile[lr + 8 + i][lc];
        f16* dst = out + (size_t)(c0 + lc) * NKIN + r0 + lr;
        *(f16x8*)dst       = a;
        *(f16x8*)(dst + 8) = b;
    }
}

// ---------------- projection: xz[t][b][g] = x[b][t][:] @ W[:][g] + bias[g] ----------------
__global__ __launch_bounds__(256)
void k_proj(const float* __restrict__ x, const f16* __restrict__ Wt,
            const float* __restrict__ bias, f16* __restrict__ xz) {
    __shared__ f16 As[128][40];
    __shared__ f16 Bs[128][40];
    const int bid = blockIdx.y * gridDim.x + blockIdx.x;   // 0..2047
    const int swz = (bid & 7) * 256 + (bid >> 3);          // XCD-contiguous chunks
    const int nb = swz & 15;
    const int tb = swz >> 4;
    const int n0 = nb * 128;
    const int tid  = threadIdx.x;
    const int lane = tid & 63;
    const int wid  = tid >> 6;
    const int wm = (wid >> 1) * 64;
    const int wn = (wid & 1) * 64;
    const int lm = lane & 15;
    const int lg = lane >> 4;

    f32x4 acc[4][4];
#pragma unroll
    for (int mi = 0; mi < 4; ++mi)
#pragma unroll
        for (int ni = 0; ni < 4; ++ni)
#pragma unroll
            for (int i = 0; i < 4; ++i) acc[mi][ni][i] = 0.0f;

    for (int kt = 0; kt < NKIN; kt += 32) {
        {
            const int brow = tid >> 1;
            const int kq   = (tid & 1) << 4;
            const float* src = x + ((size_t)brow * NTIME + tb) * NKIN + kt + kq;
            float4 v0 = ((const float4*)src)[0];
            float4 v1 = ((const float4*)src)[1];
            float4 v2 = ((const float4*)src)[2];
            float4 v3 = ((const float4*)src)[3];
            *(f16x8*)&As[brow][kq]     = pack8(v0, v1);
            *(f16x8*)&As[brow][kq + 8] = pack8(v2, v3);
        }
        {
            const int nrow = tid >> 1;
            const int kq   = (tid & 1) << 4;
            const f16* src = Wt + (size_t)(n0 + nrow) * NKIN + kt + kq;
            *(f16x8*)&Bs[nrow][kq]     = *(const f16x8*)src;
            *(f16x8*)&Bs[nrow][kq + 8] = *(const f16x8*)(src + 8);
        }
        __syncthreads();
        f16x8 a[4], b[4];
#pragma unroll
        for (int mi = 0; mi < 4; ++mi)
            a[mi] = *(const f16x8*)&As[wm + mi * 16 + lm][lg * 8];
#pragma unroll
        for (int ni = 0; ni < 4; ++ni)
            b[ni] = *(const f16x8*)&Bs[wn + ni * 16 + lm][lg * 8];
#pragma unroll
        for (int mi = 0; mi < 4; ++mi)
#pragma unroll
            for (int ni = 0; ni < 4; ++ni)
                acc[mi][ni] = __builtin_amdgcn_mfma_f32_16x16x32_f16(a[mi], b[ni], acc[mi][ni], 0, 0, 0);
        __syncthreads();
    }
#pragma unroll
    for (int mi = 0; mi < 4; ++mi) {
#pragma unroll
        for (int ni = 0; ni < 4; ++ni) {
            const int col = n0 + wn + ni * 16 + lm;
            const float bv = bias[col];
#pragma unroll
            for (int i = 0; i < 4; ++i) {
                const int brow = wm + mi * 16 + lg * 4 + i;
                xz[((size_t)tb * NBATCH + brow) * NGATE + col] = (f16)(acc[mi][ni][i] + bv);
            }
        }
    }
}

// ---------------- persistent LSTM: full-M, U in LDS, conflict-free staging ----------
// 256 blocks = 8 groups (16 batch rows) x 32 slots (16 unit-cols x 4 gates), STATIC.
// U-slice (64 gate-cols x 512) in LDS once, XOR-swizzled (r5-r8 proven layout;
// reads 2-way/free). Poll-staging uses row=tid&15 mapping -> ds_write_b128 banks
// spread over all 32 (r8/r10's row=tid>>4 was an 8-way write conflict = the 2.3e7
// SQ_LDS_BANK_CONFLICT). h[t] in rotating slot t%3, poison-poll exchange (r8).
__global__ __launch_bounds__(256, 1)
void k_lstm(const f16* __restrict__ xz, const f16* __restrict__ Ut,
            f16* __restrict__ hsl, float* __restrict__ out) {
    __shared__ f16 Us[64][512];      // 64 gate-cols x 512 k, XOR-swizzled (64KB)
    __shared__ f16 As[16][512];      // 16 h rows, XOR-swizzled (16KB)
    __shared__ float zs[4][16][17];  // gate exchange (4.25KB)
    const int bid = blockIdx.x;
    const int grp  = bid & 7;        // static batch group
    const int slot = bid >> 3;       // static unit slot 0..31
    const int r0 = grp * GROWS;
    const int u0 = slot * GUNITS;
    const int tid  = threadIdx.x;
    const int lane = tid & 63;
    const int g    = tid >> 6;       // wave id == gate (i,f,g,o)
    const int lm = lane & 15;
    const int lg = lane >> 4;

    // one-time: stage 64 U gate-cols (g*512 + u0 + j) into LDS, XOR-swizzled
#pragma unroll
    for (int i = 0; i < 16; ++i) {
        const int idx = tid + i * 256;      // 0..4095
        const int c   = idx >> 6;           // local col 0..63
        const int ck  = idx & 63;           // 8-f16 chunk
        const int gcol = (c >> 4) * NUNITS + u0 + (c & 15);
        f16x8 v = *(const f16x8*)(Ut + (size_t)gcol * NUNITS + ck * 8);
        *(f16x8*)&Us[c][(ck ^ (c & 7)) * 8] = v;
    }
    // zero As (t=0 uses h=0)
    {
        f32x4 z = {0.f, 0.f, 0.f, 0.f};
        for (int i = tid; i < 16 * 64; i += 256)
            *(f32x4*)&As[i >> 6][(i & 63) * 8] = z;
    }

    const int srow = tid >> 4;       // 0..15
    const int suu  = tid & 15;       // 0..15
    const int gidx = (r0 + srow) * NUNITS + u0 + suu;
    float c_reg = 0.0f;

    // poison chunk vector
    f32x4 pz;
    {
        const float pf = __uint_as_float((POISON << 16) | POISON);
#pragma unroll
        for (int i = 0; i < 4; ++i) pz[i] = pf;
    }

    // xz prefetch (t=0): px[i] = xz[0][r0+lg*4+i][g*512+u0+lm]
    float px[4];
    {
        const f16* xp = xz + ((size_t)(r0 + lg * 4)) * NGATE + g * NUNITS + u0 + lm;
#pragma unroll
        for (int i = 0; i < 4; ++i) px[i] = (float)xp[(size_t)i * NGATE];
    }
    __syncthreads();   // Us/As visible before t=0 MFMA

    for (int t = 0; t < NTIME; ++t) {
        const f16* hin = hsl + (size_t)((t + 2) % 3) * HSZ;   // slot of h[t-1]
        f16*      hout = hsl + (size_t)(t % 3) * HSZ;         // slot of h[t]

        if (t > 0) {
            // poll-stage: spin on own 4 chunks (64B of one h row) until poison-free.
            // row = tid&15 (not tid>>4): staging ds_write banks spread over all 32.
            {
                const int row = tid & 15;
                const int seg = tid >> 4;
                const f16* src = hin + (size_t)(r0 + row) * NUNITS + seg * 32;
                f32x4 a, b, c, d;
                for (int spin = 0; spin < 65536; ++spin) {
                    load4x16_sys(src, &a, &b, &c, &d);
                    if (chunk_clean(a) && chunk_clean(b) &&
                        chunk_clean(c) && chunk_clean(d)) break;
                }
                const int c0_ = seg * 4;
                *(f32x4*)&As[row][((c0_ + 0) ^ (row & 7)) * 8] = a;
                *(f32x4*)&As[row][((c0_ + 1) ^ (row & 7)) * 8] = b;
                *(f32x4*)&As[row][((c0_ + 2) ^ (row & 7)) * 8] = c;
                *(f32x4*)&As[row][((c0_ + 3) ^ (row & 7)) * 8] = d;
            }
            __syncthreads();
            // recycle: poison own chunk of slot (t+1)%3 (holds h[t-2]; poll success
            // of h[t-1] proves everyone finished reading it). 32 x 16B.
            if (tid < 32) {
                f16* ps = hsl + (size_t)((t + 1) % 3) * HSZ
                              + (size_t)(r0 + (tid >> 1)) * NUNITS + u0 + (tid & 1) * 8;
                store_16B_sys(ps, pz);
            }
        }

        // MFMA: wave g computes z[16 rows][16 cols] for its gate.
        // A from As, B from Us (both XOR-swizzled; reads 2-way = free).
        // 4 independent chains hide MFMA latency.
        f32x4 acc0, acc1, acc2, acc3;
#pragma unroll
        for (int i = 0; i < 4; ++i) {
            acc0[i] = px[i]; acc1[i] = 0.f; acc2[i] = 0.f; acc3[i] = 0.f;
        }
#pragma unroll
        for (int ks = 0; ks < 16; ks += 4) {
            const int ca0 = (((ks + 0) * 4 + lg) ^ (lm & 7)) * 8;
            const int ca1 = (((ks + 1) * 4 + lg) ^ (lm & 7)) * 8;
            const int ca2 = (((ks + 2) * 4 + lg) ^ (lm & 7)) * 8;
            const int ca3 = (((ks + 3) * 4 + lg) ^ (lm & 7)) * 8;
            f16x8 a0 = *(const f16x8*)&As[lm][ca0];
            f16x8 b0 = *(const f16x8*)&Us[g * 16 + lm][ca0];
            f16x8 a1 = *(const f16x8*)&As[lm][ca1];
            f16x8 b1 = *(const f16x8*)&Us[g * 16 + lm][ca1];
            f16x8 a2 = *(const f16x8*)&As[lm][ca2];
            f16x8 b2 = *(const f16x8*)&Us[g * 16 + lm][ca2];
            f16x8 a3 = *(const f16x8*)&As[lm][ca3];
            f16x8 b3 = *(const f16x8*)&Us[g * 16 + lm][ca3];
            acc0 = __builtin_amdgcn_mfma_f32_16x16x32_f16(a0, b0, acc0, 0, 0, 0);
            acc1 = __builtin_amdgcn_mfma_f32_16x16x32_f16(a1, b1, acc1, 0, 0, 0);
            acc2 = __builtin_amdgcn_mfma_f32_16x16x32_f16(a2, b2, acc2, 0, 0, 0);
            acc3 = __builtin_amdgcn_mfma_f32_16x16x32_f16(a3, b3, acc3, 0, 0, 0);
        }
        f32x4 acc = (acc0 + acc1) + (acc2 + acc3);

        // prefetch next step's xz (plain cached loads; overlaps rest of step)
        if (t + 1 < NTIME) {
            const f16* xp = xz + ((size_t)(t + 1) * NBATCH + r0 + lg * 4) * NGATE
                               + g * NUNITS + u0 + lm;
#pragma unroll
            for (int i = 0; i < 4; ++i) px[i] = (float)xp[(size_t)i * NGATE];
        }

        // gate exchange: lane (lm,lg) reg i holds z[lg*4+i][lm]
#pragma unroll
        for (int i = 0; i < 4; ++i)
            zs[g][lg * 4 + i][lm] = acc[i];
        __syncthreads();

        // state update: 256 threads = 16 rows x 16 units
        const float zi = zs[0][srow][suu];
        const float zf = zs[1][srow][suu];
        const float zg = zs[2][srow][suu];
        const float zo = zs[3][srow][suu];
        const float iv = sigmoidf_(zi);
        const float fv = sigmoidf_(zf);
        const float gv = tanhf_(zg);
        const float ov = sigmoidf_(zo);
        c_reg = fv * c_reg + iv * gv;
        const float hn = ov * tanhf_(c_reg);

        if (t == NTIME - 1) {
            out[gidx]          = hn;
            out[65536 + gidx]  = hn;
            out[131072 + gidx] = c_reg;
        } else {
            // fire-and-forget h store (wave-coalesced 2B sc0sc1); consumers
            // poll the data itself, so no drain / no flag needed
            union { f16 h; unsigned short u; } cv; cv.h = (f16)hn;
            store_u16_sys(hout + gidx, cv.u);
        }
    }
}

extern "C" void kernel_launch(void* const* d_in, const int* in_sizes, int n_in,
                              void* d_out, int out_size, void* d_ws, size_t ws_size,
                              hipStream_t stream) {
    const float* x    = (const float*)d_in[0];
    const float* W    = (const float*)d_in[1];
    const float* U    = (const float*)d_in[2];
    const float* bias = (const float*)d_in[3];
    float* out = (float*)d_out;
    char* ws = (char*)d_ws;

    size_t off = 0;
    f16* Wt = (f16*)(ws + off); off += (size_t)NGATE * NKIN * 2;
    f16* Ut = (f16*)(ws + off); off += (size_t)NGATE * NUNITS * 2;
    f16* xz = (f16*)(ws + off); off += (size_t)NTIME * NBATCH * NGATE * 2;  // [t][b][g]
    f16* hsl = (f16*)(ws + off); off += (size_t)3 * HSZ * 2;                // 3 h slots
    if (ws_size < off) return;

    k_poison<<<dim3(96), 256, 0, stream>>>(hsl);
    k_transpose<<<dim3(32, 8), 256, 0, stream>>>(W, Wt);
    k_transpose<<<dim3(32, 8), 256, 0, stream>>>(U, Ut);
    k_proj<<<dim3(16, 128), 256, 0, stream>>>(x, Wt, bias, xz);
    k_lstm<<<dim3(256), 256, 0, stream>>>(xz, Ut, hsl, out);
}

// Round 12
// 558.693 us; speedup vs baseline: 1.1202x; 1.1202x over previous
//
#include <hip/hip_runtime.h>
#include <hip/hip_bf16.h>

typedef _Float16 f16;
typedef _Float16 f16x8 __attribute__((ext_vector_type(8)));
typedef float f32x4 __attribute__((ext_vector_type(4)));

#define NBATCH 128
#define NTIME  128
#define NKIN   512
#define NUNITS 512
#define NGATE  2048

// per stream: 8 groups x 8 rows; 32 slots x 16 unit-cols (64 gate-cols)
#define GROWS  8
#define HSZ    (NBATCH * NUNITS)   // one h slot (f16 elems), shared by both streams
#define POISON 0x7C00u             // f16 +inf: impossible as h = o*tanh(c)

static __device__ __forceinline__ float sigmoidf_(float x) {
    return 1.0f / (1.0f + __expf(-x));
}
static __device__ __forceinline__ float tanhf_(float x) {
    float t = __expf(-2.0f * fabsf(x));
    float r = (1.0f - t) / (1.0f + t);
    return copysignf(r, x);
}

static __device__ __forceinline__ f16x8 pack8(float4 a, float4 b) {
    f16x8 r;
    r[0] = (f16)a.x; r[1] = (f16)a.y; r[2] = (f16)a.z; r[3] = (f16)a.w;
    r[4] = (f16)b.x; r[5] = (f16)b.y; r[6] = (f16)b.z; r[7] = (f16)b.w;
    return r;
}

// ---- MALL-coherent (sc0 sc1) ops: bypass L1+L2; device-wide; proven r3/r4/r8 ----
static __device__ __forceinline__ void store_u16_sys(void* p, unsigned short v) {
    asm volatile("global_store_short %0, %1, off sc0 sc1" :: "v"(p), "v"(v) : "memory");
}
static __device__ __forceinline__ void store_16B_sys(void* p, f32x4 v) {
    asm volatile("global_store_dwordx4 %0, %1, off sc0 sc1" :: "v"(p), "v"(v) : "memory");
}
static __device__ __forceinline__ void load2x16_sys(const void* p0, const void* p1,
                                                    f32x4* a, f32x4* b) {
    asm volatile("global_load_dwordx4 %0, %2, off sc0 sc1\n\t"
                 "global_load_dwordx4 %1, %3, off sc0 sc1\n\t"
                 "s_waitcnt vmcnt(0)"
                 : "=&v"(*a), "=&v"(*b) : "v"(p0), "v"(p1) : "memory");
}

// true if no f16 half of the 16B chunk equals the poison pattern
static __device__ __forceinline__ int chunk_clean(f32x4 v) {
#pragma unroll
    for (int i = 0; i < 4; ++i) {
        unsigned u = __float_as_uint(v[i]);
        if ((u & 0xFFFFu) == POISON || (u >> 16) == POISON) return 0;
    }
    return 1;
}

// ---------------- poison init: fill 3 h slots with f16 +inf ----------------
__global__ __launch_bounds__(256)
void k_poison(f16* __restrict__ hsl) {
    f32x4 v;
    const float pf = __uint_as_float((POISON << 16) | POISON);
#pragma unroll
    for (int i = 0; i < 4; ++i) v[i] = pf;
    const size_t i = ((size_t)blockIdx.x * 256 + threadIdx.x) * 8;
    if (i < (size_t)3 * HSZ) *(f32x4*)(hsl + i) = v;
}

// ---------------- transpose: f32 in[512][2048] -> f16 out[2048][512] ----------------
__global__ __launch_bounds__(256)
void k_transpose(const float* __restrict__ in, f16* __restrict__ out) {
    __shared__ f16 tile[64][72];
    const int c0 = blockIdx.x * 64;
    const int r0 = blockIdx.y * 64;
    const int tid = threadIdx.x;
    {
        const int lr = tid >> 2;
        const int lc = (tid & 3) << 4;
        const float* src = in + (size_t)(r0 + lr) * NGATE + c0 + lc;
        float4 v0 = ((const float4*)src)[0];
        float4 v1 = ((const float4*)src)[1];
        float4 v2 = ((const float4*)src)[2];
        float4 v3 = ((const float4*)src)[3];
        *(f16x8*)&tile[lr][lc]     = pack8(v0, v1);
        *(f16x8*)&tile[lr][lc + 8] = pack8(v2, v3);
    }
    __syncthreads();
    {
        const int lc = tid >> 2;
        const int lr = (tid & 3) << 4;
        f16x8 a, b;
#pragma unroll
        for (int i = 0; i < 8; ++i) a[i] = tile[lr + i][lc];
#pragma unroll
        for (int i = 0; i < 8; ++i) b[i] = tile[lr + 8 + i][lc];
        f16* dst = out + (size_t)(c0 + lc) * NKIN + r0 + lr;
        *(f16x8*)dst       = a;
        *(f16x8*)(dst + 8) = b;
    }
}

// ---------------- projection: xz[t][b][g] = x[b][t][:] @ W[:][g] + bias[g] ----------------
__global__ __launch_bounds__(256)
void k_proj(const float* __restrict__ x, const f16* __restrict__ Wt,
            const float* __restrict__ bias, f16* __restrict__ xz) {
    __shared__ f16 As[128][40];
    __shared__ f16 Bs[128][40];
    const int bid = blockIdx.y * gridDim.x + blockIdx.x;   // 0..2047
    const int swz = (bid & 7) * 256 + (bid >> 3);          // XCD-contiguous chunks
    const int nb = swz & 15;
    const int tb = swz >> 4;
    const int n0 = nb * 128;
    const int tid  = threadIdx.x;
    const int lane = tid & 63;
    const int wid  = tid >> 6;
    const int wm = (wid >> 1) * 64;
    const int wn = (wid & 1) * 64;
    const int lm = lane & 15;
    const int lg = lane >> 4;

    f32x4 acc[4][4];
#pragma unroll
    for (int mi = 0; mi < 4; ++mi)
#pragma unroll
        for (int ni = 0; ni < 4; ++ni)
#pragma unroll
            for (int i = 0; i < 4; ++i) acc[mi][ni][i] = 0.0f;

    for (int kt = 0; kt < NKIN; kt += 32) {
        {
            const int brow = tid >> 1;
            const int kq   = (tid & 1) << 4;
            const float* src = x + ((size_t)brow * NTIME + tb) * NKIN + kt + kq;
            float4 v0 = ((const float4*)src)[0];
            float4 v1 = ((const float4*)src)[1];
            float4 v2 = ((const float4*)src)[2];
            float4 v3 = ((const float4*)src)[3];
            *(f16x8*)&As[brow][kq]     = pack8(v0, v1);
            *(f16x8*)&As[brow][kq + 8] = pack8(v2, v3);
        }
        {
            const int nrow = tid >> 1;
            const int kq   = (tid & 1) << 4;
            const f16* src = Wt + (size_t)(n0 + nrow) * NKIN + kt + kq;
            *(f16x8*)&Bs[nrow][kq]     = *(const f16x8*)src;
            *(f16x8*)&Bs[nrow][kq + 8] = *(const f16x8*)(src + 8);
        }
        __syncthreads();
        f16x8 a[4], b[4];
#pragma unroll
        for (int mi = 0; mi < 4; ++mi)
            a[mi] = *(const f16x8*)&As[wm + mi * 16 + lm][lg * 8];
#pragma unroll
        for (int ni = 0; ni < 4; ++ni)
            b[ni] = *(const f16x8*)&Bs[wn + ni * 16 + lm][lg * 8];
#pragma unroll
        for (int mi = 0; mi < 4; ++mi)
#pragma unroll
            for (int ni = 0; ni < 4; ++ni)
                acc[mi][ni] = __builtin_amdgcn_mfma_f32_16x16x32_f16(a[mi], b[ni], acc[mi][ni], 0, 0, 0);
        __syncthreads();
    }
#pragma unroll
    for (int mi = 0; mi < 4; ++mi) {
#pragma unroll
        for (int ni = 0; ni < 4; ++ni) {
            const int col = n0 + wn + ni * 16 + lm;
            const float bv = bias[col];
#pragma unroll
            for (int i = 0; i < 4; ++i) {
                const int brow = wm + mi * 16 + lg * 4 + i;
                xz[((size_t)tb * NBATCH + brow) * NGATE + col] = (f16)(acc[mi][ni][i] + bv);
            }
        }
    }
}

// ---------------- persistent LSTM: 2-stream interleave hides MALL latency ----------
// Batch split into 2 INDEPENDENT recurrences: stream A rows 0-63, B rows 64-127.
// Every block serves BOTH streams with the same U-slice (64 gate-cols, 64KB LDS):
// per t it computes A's step, fires A's h over the MALL, then computes B's step
// while A's h is in flight (and vice versa) -> the exchange RTT hides under the
// other stream's compute. Per stream: 8 groups x 8 rows x 32 slots (16 unit-cols)
// = r8's proven shapes. Poison-poll exchange (r8): h[t] in shared slot t%3 (A in
// rows 0-63, B in rows 64-127); poll own chunks until poison-free; after polling
// h_s'[tp], poison s'-rows of slot (tp+2)%3 (safe: all-wrote[tp] => all-read[tp-1]).
__global__ __launch_bounds__(256, 1)
void k_lstm(const f16* __restrict__ xz, const f16* __restrict__ Ut,
            f16* __restrict__ hsl, float* __restrict__ out) {
    __shared__ f16 Us[64][512];      // 64 gate-cols x 512 k, XOR-swizzled (64KB)
    __shared__ f16 AsA[16][512];     // stream A h rows (8 valid + 8 zero) (16KB)
    __shared__ f16 AsB[16][512];     // stream B h rows (16KB)
    __shared__ float zs[4][GROWS][17];
    const int bid = blockIdx.x;
    const int grp  = bid & 7;
    const int slot = bid >> 3;       // 0..31
    const int r0A = grp * GROWS;         // stream A rows
    const int r0B = 64 + grp * GROWS;    // stream B rows
    const int u0 = slot * 16;        // 16 unit-cols
    const int tid  = threadIdx.x;
    const int lane = tid & 63;
    const int g    = tid >> 6;       // wave id == gate (i,f,g,o)
    const int lm = lane & 15;
    const int lg = lane >> 4;

    // one-time: stage 64 U gate-cols into LDS, XOR-swizzled (r11-verbatim)
#pragma unroll
    for (int i = 0; i < 16; ++i) {
        const int idx = tid + i * 256;      // 0..4095
        const int c   = idx >> 6;           // local col 0..63
        const int ck  = idx & 63;           // 8-f16 chunk
        const int gcol = (c >> 4) * NUNITS + u0 + (c & 15);
        f16x8 v = *(const f16x8*)(Ut + (size_t)gcol * NUNITS + ck * 8);
        *(f16x8*)&Us[c][(ck ^ (c & 7)) * 8] = v;
    }
    // zero both As (t=0 uses h=0; rows 8..15 stay zero forever)
    {
        f32x4 z = {0.f, 0.f, 0.f, 0.f};
        for (int i = tid; i < 16 * 64; i += 256) {
            *(f32x4*)&AsA[i >> 6][(i & 63) * 8] = z;
            *(f32x4*)&AsB[i >> 6][(i & 63) * 8] = z;
        }
    }

    const int srow = tid >> 4;       // state row 0..7 (tid<128)
    const int suu  = tid & 15;       // state unit 0..15
    const int gidxA = (r0A + srow) * NUNITS + u0 + suu;
    const int gidxB = (r0B + srow) * NUNITS + u0 + suu;
    float c_regA = 0.0f, c_regB = 0.0f;

    f32x4 pz;
    {
        const float pf = __uint_as_float((POISON << 16) | POISON);
#pragma unroll
        for (int i = 0; i < 4; ++i) pz[i] = pf;
    }

    // xz prefetch (t=0) for both streams: px[i] = xz[0][r0+lg*4+i][g*512+u0+lm]
    float pxA[4] = {0.f, 0.f, 0.f, 0.f};
    float pxB[4] = {0.f, 0.f, 0.f, 0.f};
    if (lg < 2) {
        const f16* xa = xz + ((size_t)(r0A + lg * 4)) * NGATE + g * NUNITS + u0 + lm;
        const f16* xb = xz + ((size_t)(r0B + lg * 4)) * NGATE + g * NUNITS + u0 + lm;
#pragma unroll
        for (int i = 0; i < 4; ++i) {
            pxA[i] = (float)xa[(size_t)i * NGATE];
            pxB[i] = (float)xb[(size_t)i * NGATE];
        }
    }
    __syncthreads();   // Us/As visible before t=0 MFMA

    for (int t = 0; t < NTIME; ++t) {
        // =================== PHASE A (stream A, time t) ===================
        {
            // MFMA: wave g -> z[8 valid rows][16 cols]; 4 chains of 4
            f32x4 a0, a1, a2, a3;
#pragma unroll
            for (int i = 0; i < 4; ++i) { a0[i] = pxA[i]; a1[i] = 0.f; a2[i] = 0.f; a3[i] = 0.f; }
#pragma unroll
            for (int ks = 0; ks < 16; ks += 4) {
                const int ca0 = (((ks + 0) * 4 + lg) ^ (lm & 7)) * 8;
                const int ca1 = (((ks + 1) * 4 + lg) ^ (lm & 7)) * 8;
                const int ca2 = (((ks + 2) * 4 + lg) ^ (lm & 7)) * 8;
                const int ca3 = (((ks + 3) * 4 + lg) ^ (lm & 7)) * 8;
                a0 = __builtin_amdgcn_mfma_f32_16x16x32_f16(*(const f16x8*)&AsA[lm][ca0],
                        *(const f16x8*)&Us[g * 16 + lm][ca0], a0, 0, 0, 0);
                a1 = __builtin_amdgcn_mfma_f32_16x16x32_f16(*(const f16x8*)&AsA[lm][ca1],
                        *(const f16x8*)&Us[g * 16 + lm][ca1], a1, 0, 0, 0);
                a2 = __builtin_amdgcn_mfma_f32_16x16x32_f16(*(const f16x8*)&AsA[lm][ca2],
                        *(const f16x8*)&Us[g * 16 + lm][ca2], a2, 0, 0, 0);
                a3 = __builtin_amdgcn_mfma_f32_16x16x32_f16(*(const f16x8*)&AsA[lm][ca3],
                        *(const f16x8*)&Us[g * 16 + lm][ca3], a3, 0, 0, 0);
            }
            f32x4 acc = (a0 + a1) + (a2 + a3);
            if (lg < 2) {
#pragma unroll
                for (int i = 0; i < 4; ++i) zs[g][lg * 4 + i][lm] = acc[i];
            }
            // prefetch pxA for t+1 (plain cached; used next iteration)
            if (t + 1 < NTIME && lg < 2) {
                const f16* xa = xz + ((size_t)(t + 1) * NBATCH + r0A + lg * 4) * NGATE
                                   + g * NUNITS + u0 + lm;
#pragma unroll
                for (int i = 0; i < 4; ++i) pxA[i] = (float)xa[(size_t)i * NGATE];
            }
        }
        __syncthreads();
        // state A (tid<128) overlapped with poll of stream B by all threads
        if (tid < 128) {
            const float zi = zs[0][srow][suu];
            const float zf = zs[1][srow][suu];
            const float zg_ = zs[2][srow][suu];
            const float zo = zs[3][srow][suu];
            const float iv = sigmoidf_(zi);
            const float fv = sigmoidf_(zf);
            const float gv = tanhf_(zg_);
            const float ov = sigmoidf_(zo);
            c_regA = fv * c_regA + iv * gv;
            const float hn = ov * tanhf_(c_regA);
            if (t == NTIME - 1) {
                out[gidxA]          = hn;
                out[65536 + gidxA]  = hn;
                out[131072 + gidxA] = c_regA;
            } else {
                union { f16 h; unsigned short u; } cv; cv.h = (f16)hn;
                store_u16_sys(hsl + (size_t)(t % 3) * HSZ + gidxA, cv.u);
            }
        }
        // poll-stage stream B's h[t-1] -> AsB (skip t=0: zeros already staged)
        if (t > 0) {
            const f16* hb = hsl + (size_t)((t + 2) % 3) * HSZ;   // slot of h[t-1]
            const int row = tid >> 5;        // 0..7
            const int c0_ = tid & 31;
            const f16* src = hb + (size_t)(r0B + row) * NUNITS;
            f32x4 a, b;
            for (int spin = 0; spin < 65536; ++spin) {
                load2x16_sys(src + c0_ * 8, src + (c0_ + 32) * 8, &a, &b);
                if (chunk_clean(a) && chunk_clean(b)) break;
            }
            *(f32x4*)&AsB[row][(c0_ ^ (row & 7)) * 8]        = a;
            *(f32x4*)&AsB[row][((c0_ + 32) ^ (row & 7)) * 8] = b;
            // poison B-rows of slot (t+1)%3 (= (tp+2)%3 for tp=t-1)
            if (tid < 16) {
                f16* ps = hsl + (size_t)((t + 1) % 3) * HSZ
                              + (size_t)(r0B + (tid >> 1)) * NUNITS + u0 + (tid & 1) * 8;
                store_16B_sys(ps, pz);
            }
        }
        __syncthreads();

        // =================== PHASE B (stream B, time t) ===================
        {
            f32x4 a0, a1, a2, a3;
#pragma unroll
            for (int i = 0; i < 4; ++i) { a0[i] = pxB[i]; a1[i] = 0.f; a2[i] = 0.f; a3[i] = 0.f; }
#pragma unroll
            for (int ks = 0; ks < 16; ks += 4) {
                const int ca0 = (((ks + 0) * 4 + lg) ^ (lm & 7)) * 8;
                const int ca1 = (((ks + 1) * 4 + lg) ^ (lm & 7)) * 8;
                const int ca2 = (((ks + 2) * 4 + lg) ^ (lm & 7)) * 8;
                const int ca3 = (((ks + 3) * 4 + lg) ^ (lm & 7)) * 8;
                a0 = __builtin_amdgcn_mfma_f32_16x16x32_f16(*(const f16x8*)&AsB[lm][ca0],
                        *(const f16x8*)&Us[g * 16 + lm][ca0], a0, 0, 0, 0);
                a1 = __builtin_amdgcn_mfma_f32_16x16x32_f16(*(const f16x8*)&AsB[lm][ca1],
                        *(const f16x8*)&Us[g * 16 + lm][ca1], a1, 0, 0, 0);
                a2 = __builtin_amdgcn_mfma_f32_16x16x32_f16(*(const f16x8*)&AsB[lm][ca2],
                        *(const f16x8*)&Us[g * 16 + lm][ca2], a2, 0, 0, 0);
                a3 = __builtin_amdgcn_mfma_f32_16x16x32_f16(*(const f16x8*)&AsB[lm][ca3],
                        *(const f16x8*)&Us[g * 16 + lm][ca3], a3, 0, 0, 0);
            }
            f32x4 acc = (a0 + a1) + (a2 + a3);
            if (lg < 2) {
#pragma unroll
                for (int i = 0; i < 4; ++i) zs[g][lg * 4 + i][lm] = acc[i];
            }
            if (t + 1 < NTIME && lg < 2) {
                const f16* xb = xz + ((size_t)(t + 1) * NBATCH + r0B + lg * 4) * NGATE
                                   + g * NUNITS + u0 + lm;
#pragma unroll
                for (int i = 0; i < 4; ++i) pxB[i] = (float)xb[(size_t)i * NGATE];
            }
        }
        __syncthreads();
        // state B overlapped with poll of stream A's h[t] (just stored in phase A)
        if (tid < 128) {
            const float zi = zs[0][srow][suu];
            const float zf = zs[1][srow][suu];
            const float zg_ = zs[2][srow][suu];
            const float zo = zs[3][srow][suu];
            const float iv = sigmoidf_(zi);
            const float fv = sigmoidf_(zf);
            const float gv = tanhf_(zg_);
            const float ov = sigmoidf_(zo);
            c_regB = fv * c_regB + iv * gv;
            const float hn = ov * tanhf_(c_regB);
            if (t == NTIME - 1) {
                out[gidxB]          = hn;
                out[65536 + gidxB]  = hn;
                out[131072 + gidxB] = c_regB;
            } else {
                union { f16 h; unsigned short u; } cv; cv.h = (f16)hn;
                store_u16_sys(hsl + (size_t)(t % 3) * HSZ + gidxB, cv.u);
            }
        }
        // poll-stage stream A's h[t] -> AsA for (A, t+1); skip on last iteration
        if (t + 1 < NTIME) {
            const f16* ha = hsl + (size_t)(t % 3) * HSZ;         // slot of h_A[t]
            const int row = tid >> 5;
            const int c0_ = tid & 31;
            const f16* src = ha + (size_t)(r0A + row) * NUNITS;
            f32x4 a, b;
            for (int spin = 0; spin < 65536; ++spin) {
                load2x16_sys(src + c0_ * 8, src + (c0_ + 32) * 8, &a, &b);
                if (chunk_clean(a) && chunk_clean(b)) break;
            }
            *(f32x4*)&AsA[row][(c0_ ^ (row & 7)) * 8]        = a;
            *(f32x4*)&AsA[row][((c0_ + 32) ^ (row & 7)) * 8] = b;
            // poison A-rows of slot (t+2)%3 (= (tp+2)%3 for tp=t)
            if (tid < 16) {
                f16* ps = hsl + (size_t)((t + 2) % 3) * HSZ
                              + (size_t)(r0A + (tid >> 1)) * NUNITS + u0 + (tid & 1) * 8;
                store_16B_sys(ps, pz);
            }
        }
        __syncthreads();
    }
}

extern "C" void kernel_launch(void* const* d_in, const int* in_sizes, int n_in,
                              void* d_out, int out_size, void* d_ws, size_t ws_size,
                              hipStream_t stream) {
    const float* x    = (const float*)d_in[0];
    const float* W    = (const float*)d_in[1];
    const float* U    = (const float*)d_in[2];
    const float* bias = (const float*)d_in[3];
    float* out = (float*)d_out;
    char* ws = (char*)d_ws;

    size_t off = 0;
    f16* Wt = (f16*)(ws + off); off += (size_t)NGATE * NKIN * 2;
    f16* Ut = (f16*)(ws + off); off += (size_t)NGATE * NUNITS * 2;
    f16* xz = (f16*)(ws + off); off += (size_t)NTIME * NBATCH * NGATE * 2;  // [t][b][g]
    f16* hsl = (f16*)(ws + off); off += (size_t)3 * HSZ * 2;                // 3 h slots
    if (ws_size < off) return;

    k_poison<<<dim3(96), 256, 0, stream>>>(hsl);
    k_transpose<<<dim3(32, 8), 256, 0, stream>>>(W, Wt);
    k_transpose<<<dim3(32, 8), 256, 0, stream>>>(U, Ut);
    k_proj<<<dim3(16, 128), 256, 0, stream>>>(x, Wt, bias, xz);
    k_lstm<<<dim3(256), 256, 0, stream>>>(xz, Ut, hsl, out);
}